// Round 3
// baseline (737.883 us; speedup 1.0000x reference)
//
#include <hip/hip_runtime.h>
#include <math.h>

#define N_S   1024
#define N_T   1024
#define C_IN  128
#define E_EDG 16384
#define R     32
#define NSTEP 2

// ---- phase-aliased LDS ------------------------------------------------------
struct LdsPre  { float wa[512]; float wt[64][129]; float red[256]; };
struct LdsYs   { float x[4][128]; };
struct LdsPost { float w3[1024]; float wm1[1024]; float ul[8][33]; float ol[8][33]; };
struct LdsShat { float As[64][132]; float Bs[64][132]; };
struct LdsRt   { float Sl[16][68]; float Rl[16][36]; float mrow[64]; float irow[64]; };
struct LdsDelta{ float Pl[64][36]; float Ql[64][36]; };
union  LdsAll  { LdsPre pre; LdsYs ys; LdsPost post; LdsShat shat; LdsRt rtl; LdsDelta del; };

// ---------------------------------------------------------------------------
// Manual grid barrier: monotonic counter, device-scope atomics + fences.
// All 256 blocks are provably co-resident (4 waves, 67.6KB LDS, 1-2 blk/CU),
// so the spin cannot deadlock. Bounded spin as a failsafe.
// ---------------------------------------------------------------------------
__device__ __forceinline__ void gbar(unsigned* cnt, unsigned target) {
    __threadfence();                       // release this block's writes (agent scope)
    __syncthreads();
    if (threadIdx.x == 0) {
        atomicAdd(cnt, 1u);                // device-scope arrive
        unsigned spin = 0;
        while (__hip_atomic_load(cnt, __ATOMIC_ACQUIRE,
                                 __HIP_MEMORY_SCOPE_AGENT) < target) {
            __builtin_amdgcn_s_sleep(2);
            if (++spin > (1u << 27)) break;   // failsafe: fail loud, not hung
        }
    }
    __syncthreads();
    __threadfence();                       // acquire side for all threads
}

// ---------------------------------------------------------------------------
// One persistent kernel: 256 blocks x 256 threads, phases split by gbar().
// Phase math is identical to the verified R1 multi-kernel version.
// ---------------------------------------------------------------------------
__global__ __launch_bounds__(256, 1) void mega(
    const float* __restrict__ inputs, const int* __restrict__ idx1,
    const int* __restrict__ idx2, const int* __restrict__ es,
    const int* __restrict__ et, const float* __restrict__ W1,
    const float* __restrict__ W2, const float* __restrict__ W3,
    const float* __restrict__ b3, const float* __restrict__ Wm1,
    const float* __restrict__ bm1, const float* __restrict__ Wm2,
    const float* __restrict__ bm2, const float* __restrict__ rs_all,
    float* out,
    float* Shat, float2* part, float* Ys, float* G,
    float* rt, float* aggt, float* aggs0, float* aggs1,
    float* P0, float* P1, float* Q, unsigned* bar) {

    __shared__ LdsAll lds;
    const int bid = blockIdx.x;
    const int t   = threadIdx.x;
    unsigned tgt = 0;

    // ---- P0: G = W1 W1^T + W2 W2^T (blocks 0..127); zero rt..aggs1 (128..255)
    if (bid >= 128) {
        // rt, aggt, aggs0, aggs1 contiguous: 131072 floats = 32768 float4
        ((float4*)rt)[(bid - 128) * 256 + t] = make_float4(0.f, 0.f, 0.f, 0.f);
    } else {
        LdsPre& L = lds.pre;
        const int a = bid;
        for (int s = t; s < 512; s += 256)
            L.wa[s] = (s < 256) ? W1[a * 256 + s] : W2[a * 256 + (s - 256)];
        __syncthreads();
        float acc = 0.f;
        const int b = t & 127, h = t >> 7;
        for (int ci = 0; ci < 8; ++ci) {
            const float* Wsrc = (ci < 4) ? W1 : W2;
            const int cbase = (ci & 3) * 64;
#pragma unroll
            for (int it = 0; it < 8; ++it) {
                int s = it * 256 + t;
                int br = s >> 4, q = s & 15;
                float4 v = *(const float4*)(Wsrc + (size_t)br * 256 + cbase + q * 4);
                L.wt[q * 4 + 0][br] = v.x; L.wt[q * 4 + 1][br] = v.y;
                L.wt[q * 4 + 2][br] = v.z; L.wt[q * 4 + 3][br] = v.w;
            }
            __syncthreads();
            const float* wac = L.wa + ci * 64 + h * 32;
#pragma unroll
            for (int cc = 0; cc < 32; ++cc)
                acc += wac[cc] * L.wt[h * 32 + cc][b];
            __syncthreads();
        }
        L.red[t] = acc;
        __syncthreads();
        if (t < 128) G[a * 128 + t] = L.red[t] + L.red[t + 128];
    }
    gbar(bar, tgt += 256);

    // ---- P1: Ys = X[idx1] @ G (4 rows/block)  +  s-graph scatter (both steps)
    {
        LdsYs& L = lds.ys;
        const int i0 = bid * 4;
        for (int s = t; s < 512; s += 256)
            L.x[s >> 7][s & 127] = inputs[(size_t)idx1[i0 + (s >> 7)] * 128 + (s & 127)];
        __syncthreads();
        const int lr = t >> 7, a = t & 127;
        for (int p = 0; p < 2; ++p) {
            const int row = p * 2 + lr;
            float acc = 0.f;
#pragma unroll 8
            for (int d = 0; d < 128; ++d) acc += L.x[row][d] * G[d * 128 + a];
            Ys[(size_t)(i0 + row) * 128 + a] = acc;
        }
    }
    {
        const int gid = bid * 256 + t;
        for (int v = gid; v < 2 * E_EDG * 32; v += 65536) {
            int k = v & 31, ei = v >> 5;
            int step = ei >> 14, e = ei & (E_EDG - 1);
            int src = es[e], dst = es[E_EDG + e];
            const float* rs = rs_all + (size_t)step * N_S * R;
            float* aggs = step ? aggs1 : aggs0;
            atomicAdd(&aggs[(size_t)dst * 32 + k], rs[(size_t)src * 32 + k]);
        }
    }
    gbar(bar, tgt += 256);

    // ---- P2: post_s (P0/P1 for both steps, 8 rows/block) then Shat tile
    {
        LdsPost& L = lds.post;
        for (int s = t; s < 1024; s += 256) { L.w3[s] = W3[s]; L.wm1[s] = Wm1[s]; }
        const int row8 = t >> 5, k = t & 31;
        const int grow = bid * 8 + row8;        // 0..2047
        const int step = grow >> 10, r = grow & 1023;
        const float* rs = rs_all + (size_t)step * N_S * R;
        const float* agg = step ? aggs1 : aggs0;
        float* P = step ? P1 : P0;
        L.ul[row8][k] = rs[(size_t)r * 32 + k] + agg[(size_t)r * 32 + k];
        __syncthreads();
        float acc = b3[k];
#pragma unroll
        for (int m = 0; m < 32; ++m) acc += L.ul[row8][m] * L.w3[m * 32 + k];
        L.ol[row8][k] = fmaxf(acc, 0.f);
        __syncthreads();
        float acc2 = bm1[k];
#pragma unroll
        for (int m = 0; m < 32; ++m) acc2 += L.ol[row8][m] * L.wm1[m * 32 + k];
        P[(size_t)r * 32 + k] = acc2;
        __syncthreads();                         // LDS reuse barrier
    }
    {
        LdsShat& L = lds.shat;
        const int i0 = (bid >> 4) * 64, j0 = (bid & 15) * 64, jt = bid & 15;
        for (int s = t; s < 64 * 32; s += 256) {
            int row = s >> 5, q = s & 31;
            *(float4*)&L.As[row][q * 4] =
                ((const float4*)(Ys + (size_t)(i0 + row) * 128))[q];
        }
        for (int s = t; s < 64 * 32; s += 256) {
            int row = s >> 5, q = s & 31;
            int src = idx2[j0 + row];
            *(float4*)&L.Bs[row][q * 4] =
                ((const float4*)(inputs + (size_t)src * 128))[q];
        }
        __syncthreads();
        const int r = t >> 4, c = t & 15;
        float acc[4][4] = {};
        for (int k = 0; k < 128; k += 4) {
            float4 ya[4], xb[4];
#pragma unroll
            for (int a = 0; a < 4; ++a) ya[a] = *(const float4*)&L.As[r + 16 * a][k];
#pragma unroll
            for (int b = 0; b < 4; ++b) xb[b] = *(const float4*)&L.Bs[c + 16 * b][k];
#pragma unroll
            for (int a = 0; a < 4; ++a)
#pragma unroll
                for (int b = 0; b < 4; ++b)
                    acc[a][b] += ya[a].x * xb[b].x + ya[a].y * xb[b].y +
                                 ya[a].z * xb[b].z + ya[a].w * xb[b].w;
        }
#pragma unroll
        for (int a = 0; a < 4; ++a) {
#pragma unroll
            for (int b = 0; b < 4; ++b)
                Shat[(size_t)(i0 + r + 16 * a) * 1024 + (j0 + c + 16 * b)] = acc[a][b];
            float M = fmaxf(fmaxf(acc[a][0], acc[a][1]), fmaxf(acc[a][2], acc[a][3]));
#pragma unroll
            for (int m = 1; m < 16; m <<= 1) M = fmaxf(M, __shfl_xor(M, m, 16));
            float Ss = 0.f;
#pragma unroll
            for (int b = 0; b < 4; ++b) Ss += __expf(acc[a][b] - M);
#pragma unroll
            for (int m = 1; m < 16; m <<= 1) Ss += __shfl_xor(Ss, m, 16);
            if (c == 0)
                part[(size_t)(i0 + r + 16 * a) * 16 + jt] = make_float2(M, Ss);
        }
    }
    gbar(bar, tgt += 256);

    // ---- consensus steps
    for (int step = 0; step < NSTEP; ++step) {
        const float* rs   = rs_all + (size_t)step * N_S * R;
        const float* Pcur = step ? P1 : P0;
        float* out0 = (step == 0) ? out : nullptr;

        // P3: rt[j,k] += sum_i softmax(Shat)[i,j]*rs[i,k] (64 i x 64 j / block)
        {
            LdsRt& L = lds.rtl;
            const int j0 = (bid & 15) * 64;
            const int i0 = (bid >> 4) * 64;
            if (t < 64) {
                const float2* pr = part + (size_t)(i0 + t) * 16;
                float M = -1e30f, S = 0.f;
                float2 ps[16];
#pragma unroll
                for (int q = 0; q < 16; ++q) { ps[q] = pr[q]; M = fmaxf(M, ps[q].x); }
#pragma unroll
                for (int q = 0; q < 16; ++q) S += ps[q].y * __expf(ps[q].x - M);
                L.mrow[t] = M;
                L.irow[t] = 1.f / S;
            }
            __syncthreads();
            const int k = t & 31, jg = t >> 5;
            float acc[8] = {};
            for (int ic = 0; ic < 64; ic += 16) {
                {
                    int row = t >> 4, q = t & 15;   // 16 rows x 16 float4
                    int lr = ic + row;
                    float4 v = ((const float4*)(Shat + (size_t)(i0 + lr) * 1024 + j0))[q];
                    float m = L.mrow[lr], inv = L.irow[lr];
                    v.x = __expf(v.x - m) * inv;
                    v.y = __expf(v.y - m) * inv;
                    v.z = __expf(v.z - m) * inv;
                    v.w = __expf(v.w - m) * inv;
                    *(float4*)&L.Sl[row][q * 4] = v;
                    if (out0)
                        ((float4*)(out0 + (size_t)(i0 + lr) * 1024 + j0))[q] = v;
                }
                if (t < 128) {
                    int row = t >> 3, q = t & 7;   // 16 rows x 8 float4
                    *(float4*)&L.Rl[row][q * 4] =
                        ((const float4*)(rs + (size_t)(i0 + ic + row) * 32))[q];
                }
                __syncthreads();
#pragma unroll
                for (int ii = 0; ii < 16; ++ii) {
                    float rv = L.Rl[ii][k];
#pragma unroll
                    for (int m = 0; m < 8; ++m)
                        acc[m] += L.Sl[ii][jg * 8 + m] * rv;
                }
                __syncthreads();
            }
#pragma unroll
            for (int m = 0; m < 8; ++m)
                atomicAdd(&rt[(size_t)(j0 + jg * 8 + m) * 32 + k], acc[m]);
        }
        gbar(bar, tgt += 256);

        // P4: t-graph scatter
        {
            const int gid = bid * 256 + t;
            for (int v = gid; v < E_EDG * 32; v += 65536) {
                int k = v & 31, e = v >> 5;
                int src = et[e], dst = et[E_EDG + e];
                atomicAdd(&aggt[(size_t)dst * 32 + k], rt[(size_t)src * 32 + k]);
            }
        }
        gbar(bar, tgt += 256);

        // P5: Q = relu((rt+aggt)@W3+b3) @ Wm1  (blocks 0..127, 8 rows each)
        if (bid < 128) {
            LdsPost& L = lds.post;
            for (int s = t; s < 1024; s += 256) { L.w3[s] = W3[s]; L.wm1[s] = Wm1[s]; }
            const int row8 = t >> 5, k = t & 31;
            const int r = bid * 8 + row8;
            L.ul[row8][k] = rt[(size_t)r * 32 + k] + aggt[(size_t)r * 32 + k];
            __syncthreads();
            float acc = b3[k];
#pragma unroll
            for (int m = 0; m < 32; ++m) acc += L.ul[row8][m] * L.w3[m * 32 + k];
            L.ol[row8][k] = fmaxf(acc, 0.f);
            __syncthreads();
            float acc2 = 0.f;
#pragma unroll
            for (int m = 0; m < 32; ++m) acc2 += L.ol[row8][m] * L.wm1[m * 32 + k];
            Q[(size_t)r * 32 + k] = acc2;
        }
        gbar(bar, tgt += 256);

        // P6: Shat += delta, emit new partials; zero rt+aggt for next step
        {
            LdsDelta& L = lds.del;
            if (t < 64)   // rt+aggt contiguous: 65536 floats = 16384 float4
                ((float4*)rt)[bid * 64 + t] = make_float4(0.f, 0.f, 0.f, 0.f);
            const int i0 = (bid >> 4) * 64, j0 = (bid & 15) * 64, jt = bid & 15;
            for (int s = t; s < 64 * 8; s += 256) {
                int row = s >> 3, q = s & 7;
                *(float4*)&L.Pl[row][q * 4] =
                    ((const float4*)(Pcur + (size_t)(i0 + row) * 32))[q];
                *(float4*)&L.Ql[row][q * 4] =
                    ((const float4*)(Q + (size_t)(j0 + row) * 32))[q];
            }
            __syncthreads();
            const int r = t >> 4, c = t & 15;
            const float bv = bm2[0];
            float acc[4][4] = {};
#pragma unroll
            for (int q = 0; q < 8; ++q) {
                float4 w = ((const float4*)Wm2)[q];
                float4 pa[4], qb[4];
#pragma unroll
                for (int a = 0; a < 4; ++a) pa[a] = *(const float4*)&L.Pl[r + 16 * a][q * 4];
#pragma unroll
                for (int b = 0; b < 4; ++b) qb[b] = *(const float4*)&L.Ql[c + 16 * b][q * 4];
#pragma unroll
                for (int a = 0; a < 4; ++a)
#pragma unroll
                    for (int b = 0; b < 4; ++b)
                        acc[a][b] += w.x * fmaxf(pa[a].x - qb[b].x, 0.f)
                                   + w.y * fmaxf(pa[a].y - qb[b].y, 0.f)
                                   + w.z * fmaxf(pa[a].z - qb[b].z, 0.f)
                                   + w.w * fmaxf(pa[a].w - qb[b].w, 0.f);
            }
#pragma unroll
            for (int a = 0; a < 4; ++a) {
                float v[4];
#pragma unroll
                for (int b = 0; b < 4; ++b) {
                    size_t idx = (size_t)(i0 + r + 16 * a) * 1024 + (j0 + c + 16 * b);
                    v[b] = Shat[idx] + acc[a][b] + bv;
                    Shat[idx] = v[b];
                }
                float M = fmaxf(fmaxf(v[0], v[1]), fmaxf(v[2], v[3]));
#pragma unroll
                for (int m = 1; m < 16; m <<= 1) M = fmaxf(M, __shfl_xor(M, m, 16));
                float Ss = 0.f;
#pragma unroll
                for (int b = 0; b < 4; ++b) Ss += __expf(v[b] - M);
#pragma unroll
                for (int m = 1; m < 16; m <<= 1) Ss += __shfl_xor(Ss, m, 16);
                if (c == 0)
                    part[(size_t)(i0 + r + 16 * a) * 16 + jt] = make_float2(M, Ss);
            }
        }
        gbar(bar, tgt += 256);
    }

    // ---- P7: final softmax S_L from partials (4 rows/block)
    {
        float* out2 = out + (1 << 20);
        for (int rl = 0; rl < 4; ++rl) {
            const int i = bid * 4 + rl;
            const float2* pr = part + (size_t)i * 16;
            float M = -1e30f, S = 0.f;
            float2 ps[16];
#pragma unroll
            for (int q = 0; q < 16; ++q) { ps[q] = pr[q]; M = fmaxf(M, ps[q].x); }
#pragma unroll
            for (int q = 0; q < 16; ++q) S += ps[q].y * __expf(ps[q].x - M);
            const float inv = 1.f / S;
            const float* row = Shat + (size_t)i * 1024;
            float* o = out2 + (size_t)i * 1024;
#pragma unroll
            for (int j = 0; j < 4; ++j)
                o[t + 256 * j] = __expf(row[t + 256 * j] - M) * inv;
        }
    }
}

// ---------------------------------------------------------------------------
extern "C" void kernel_launch(void* const* d_in, const int* in_sizes, int n_in,
                              void* d_out, int out_size, void* d_ws, size_t ws_size,
                              hipStream_t stream) {
    const float* inputs = (const float*)d_in[0];
    const int*   idx1   = (const int*)d_in[1];
    const int*   idx2   = (const int*)d_in[2];
    const int*   es     = (const int*)d_in[3];
    const int*   et     = (const int*)d_in[4];
    const float* W1     = (const float*)d_in[5];
    const float* W2     = (const float*)d_in[6];
    const float* W3     = (const float*)d_in[7];
    const float* b3     = (const float*)d_in[8];
    const float* Wm1    = (const float*)d_in[9];
    const float* bm1    = (const float*)d_in[10];
    const float* Wm2    = (const float*)d_in[11];
    const float* bm2    = (const float*)d_in[12];
    const float* rs_all = (const float*)d_in[13];
    float* out = (float*)d_out;
    float* ws  = (float*)d_ws;

    // workspace layout (floats)
    float*  Shat  = ws;                       // 1,048,576
    float*  Ys    = Shat + (1 << 20);         // 131,072
    float*  G     = Ys + 131072;              // 16,384
    float2* part  = (float2*)(G + 16384);     // 32,768 floats
    float*  rt    = G + 16384 + 32768;        // 32,768  ┐ contiguous zero range
    float*  aggt  = rt + 32768;               // 32,768  │ (rt..aggs1)
    float*  aggs0 = aggt + 32768;             // 32,768  │
    float*  aggs1 = aggs0 + 32768;            // 32,768  ┘
    float*  P0    = aggs1 + 32768;            // 32,768
    float*  P1    = P0 + 32768;               // 32,768
    float*  Q     = P1 + 32768;               // 32,768
    unsigned* bar = (unsigned*)(Q + 32768);   // barrier counter (zeroed below)

    hipMemsetAsync(bar, 0, 128, stream);
    mega<<<256, 256, 0, stream>>>(inputs, idx1, idx2, es, et, W1, W2, W3, b3,
                                  Wm1, bm1, Wm2, bm2, rs_all, out,
                                  Shat, part, Ys, G, rt, aggt, aggs0, aggs1,
                                  P0, P1, Q, bar);
}

// Round 5
// 332.738 us; speedup vs baseline: 2.2176x; 2.2176x over previous
//
#include <hip/hip_runtime.h>
#include <math.h>

#define N_S   1024
#define N_T   1024
#define C_IN  128
#define E_EDG 16384
#define R     32
#define NSTEP 2

// ---- phase-aliased LDS ------------------------------------------------------
struct LdsPre  { float wa[512]; float wt[64][129]; float red[256]; };
struct LdsYs   { float x[4][128]; };
struct LdsPost { float w3[1024]; float wm1[1024]; float ul[8][33]; float ol[8][33]; };
struct LdsShat { float As[64][132]; float Bs[64][132]; };
struct LdsRt   { float Sl[16][68]; float Rl[16][36]; float mrow[64]; float irow[64]; };
struct LdsDelta{ float Pl[64][36]; float Ql[64][36]; };
union  LdsAll  { LdsPre pre; LdsYs ys; LdsPost post; LdsShat shat; LdsRt rtl; LdsDelta del; };

// ---------------------------------------------------------------------------
// Grid barrier, cheap version. ONE release RMW (single L2 writeback) + ONE
// acquire fence (single invalidate) per block per barrier, thread 0 only.
// Spin uses RELAXED loads (no per-poll invalidate) + s_sleep. All 256 blocks
// provably co-resident (4 waves, 66KB LDS -> 1 block/CU min): no deadlock;
// bounded spin as fail-loud failsafe.
// ---------------------------------------------------------------------------
__device__ __forceinline__ void gbar(unsigned* cnt, unsigned target) {
    __syncthreads();   // all waves drained before arrive
    if (threadIdx.x == 0) {
        __hip_atomic_fetch_add(cnt, 1u, __ATOMIC_RELEASE,
                               __HIP_MEMORY_SCOPE_AGENT);
        unsigned spin = 0;
        while (__hip_atomic_load(cnt, __ATOMIC_RELAXED,
                                 __HIP_MEMORY_SCOPE_AGENT) < target) {
            __builtin_amdgcn_s_sleep(8);
            if (++spin > (1u << 22)) break;   // fail loud, not hung
        }
        __builtin_amdgcn_fence(__ATOMIC_ACQUIRE, "agent");
    }
    __syncthreads();
}

// ---------------------------------------------------------------------------
// One persistent kernel: 256 blocks x 256 threads, phases split by gbar().
// Phase math identical to the R3 version that passed correctness.
// ---------------------------------------------------------------------------
__global__ __launch_bounds__(256, 1) void mega(
    const float* __restrict__ inputs, const int* __restrict__ idx1,
    const int* __restrict__ idx2, const int* __restrict__ es,
    const int* __restrict__ et, const float* __restrict__ W1,
    const float* __restrict__ W2, const float* __restrict__ W3,
    const float* __restrict__ b3, const float* __restrict__ Wm1,
    const float* __restrict__ bm1, const float* __restrict__ Wm2,
    const float* __restrict__ bm2, const float* __restrict__ rs_all,
    float* out,
    float* Shat, float2* part, float* Ys, float* G,
    float* rt, float* aggt, float* aggs0, float* aggs1,
    float* P0, float* P1, float* Q, unsigned* bar) {

    __shared__ LdsAll lds;
    const int bid = blockIdx.x;
    const int t   = threadIdx.x;
    unsigned tgt = 0;

    // ---- P0: G = W1 W1^T + W2 W2^T (blocks 0..127); zero rt..aggs1 (128..255)
    if (bid >= 128) {
        ((float4*)rt)[(bid - 128) * 256 + t] = make_float4(0.f, 0.f, 0.f, 0.f);
    } else {
        LdsPre& L = lds.pre;
        const int a = bid;
        for (int s = t; s < 512; s += 256)
            L.wa[s] = (s < 256) ? W1[a * 256 + s] : W2[a * 256 + (s - 256)];
        __syncthreads();
        float acc = 0.f;
        const int b = t & 127, h = t >> 7;
        for (int ci = 0; ci < 8; ++ci) {
            const float* Wsrc = (ci < 4) ? W1 : W2;
            const int cbase = (ci & 3) * 64;
#pragma unroll
            for (int it = 0; it < 8; ++it) {
                int s = it * 256 + t;
                int br = s >> 4, q = s & 15;
                float4 v = *(const float4*)(Wsrc + (size_t)br * 256 + cbase + q * 4);
                L.wt[q * 4 + 0][br] = v.x; L.wt[q * 4 + 1][br] = v.y;
                L.wt[q * 4 + 2][br] = v.z; L.wt[q * 4 + 3][br] = v.w;
            }
            __syncthreads();
            const float* wac = L.wa + ci * 64 + h * 32;
#pragma unroll
            for (int cc = 0; cc < 32; ++cc)
                acc += wac[cc] * L.wt[h * 32 + cc][b];
            __syncthreads();
        }
        L.red[t] = acc;
        __syncthreads();
        if (t < 128) G[a * 128 + t] = L.red[t] + L.red[t + 128];
    }
    gbar(bar, tgt += 256);

    // ---- P1: Ys = X[idx1] @ G (4 rows/block)  +  s-graph scatter (both steps)
    {
        LdsYs& L = lds.ys;
        const int i0 = bid * 4;
        for (int s = t; s < 512; s += 256)
            L.x[s >> 7][s & 127] = inputs[(size_t)idx1[i0 + (s >> 7)] * 128 + (s & 127)];
        __syncthreads();
        const int lr = t >> 7, a = t & 127;
        for (int p = 0; p < 2; ++p) {
            const int row = p * 2 + lr;
            float acc = 0.f;
#pragma unroll 8
            for (int d = 0; d < 128; ++d) acc += L.x[row][d] * G[d * 128 + a];
            Ys[(size_t)(i0 + row) * 128 + a] = acc;
        }
    }
    {
        const int gid = bid * 256 + t;
        for (int v = gid; v < 2 * E_EDG * 32; v += 65536) {
            int k = v & 31, ei = v >> 5;
            int step = ei >> 14, e = ei & (E_EDG - 1);
            int src = es[e], dst = es[E_EDG + e];
            const float* rs = rs_all + (size_t)step * N_S * R;
            float* aggs = step ? aggs1 : aggs0;
            atomicAdd(&aggs[(size_t)dst * 32 + k], rs[(size_t)src * 32 + k]);
        }
    }
    gbar(bar, tgt += 256);

    // ---- P2: post_s (P0/P1 for both steps, 8 rows/block) then Shat tile
    {
        LdsPost& L = lds.post;
        for (int s = t; s < 1024; s += 256) { L.w3[s] = W3[s]; L.wm1[s] = Wm1[s]; }
        const int row8 = t >> 5, k = t & 31;
        const int grow = bid * 8 + row8;        // 0..2047
        const int step = grow >> 10, r = grow & 1023;
        const float* rs = rs_all + (size_t)step * N_S * R;
        const float* agg = step ? aggs1 : aggs0;
        float* P = step ? P1 : P0;
        L.ul[row8][k] = rs[(size_t)r * 32 + k] + agg[(size_t)r * 32 + k];
        __syncthreads();
        float acc = b3[k];
#pragma unroll
        for (int m = 0; m < 32; ++m) acc += L.ul[row8][m] * L.w3[m * 32 + k];
        L.ol[row8][k] = fmaxf(acc, 0.f);
        __syncthreads();
        float acc2 = bm1[k];
#pragma unroll
        for (int m = 0; m < 32; ++m) acc2 += L.ol[row8][m] * L.wm1[m * 32 + k];
        P[(size_t)r * 32 + k] = acc2;
        __syncthreads();                         // LDS reuse barrier
    }
    {
        LdsShat& L = lds.shat;
        const int i0 = (bid >> 4) * 64, j0 = (bid & 15) * 64, jt = bid & 15;
        for (int s = t; s < 64 * 32; s += 256) {
            int row = s >> 5, q = s & 31;
            *(float4*)&L.As[row][q * 4] =
                ((const float4*)(Ys + (size_t)(i0 + row) * 128))[q];
        }
        for (int s = t; s < 64 * 32; s += 256) {
            int row = s >> 5, q = s & 31;
            int src = idx2[j0 + row];
            *(float4*)&L.Bs[row][q * 4] =
                ((const float4*)(inputs + (size_t)src * 128))[q];
        }
        __syncthreads();
        const int r = t >> 4, c = t & 15;
        float acc[4][4] = {};
        for (int k = 0; k < 128; k += 4) {
            float4 ya[4], xb[4];
#pragma unroll
            for (int a = 0; a < 4; ++a) ya[a] = *(const float4*)&L.As[r + 16 * a][k];
#pragma unroll
            for (int b = 0; b < 4; ++b) xb[b] = *(const float4*)&L.Bs[c + 16 * b][k];
#pragma unroll
            for (int a = 0; a < 4; ++a)
#pragma unroll
                for (int b = 0; b < 4; ++b)
                    acc[a][b] += ya[a].x * xb[b].x + ya[a].y * xb[b].y +
                                 ya[a].z * xb[b].z + ya[a].w * xb[b].w;
        }
#pragma unroll
        for (int a = 0; a < 4; ++a) {
#pragma unroll
            for (int b = 0; b < 4; ++b)
                Shat[(size_t)(i0 + r + 16 * a) * 1024 + (j0 + c + 16 * b)] = acc[a][b];
            float M = fmaxf(fmaxf(acc[a][0], acc[a][1]), fmaxf(acc[a][2], acc[a][3]));
#pragma unroll
            for (int m = 1; m < 16; m <<= 1) M = fmaxf(M, __shfl_xor(M, m, 16));
            float Ss = 0.f;
#pragma unroll
            for (int b = 0; b < 4; ++b) Ss += __expf(acc[a][b] - M);
#pragma unroll
            for (int m = 1; m < 16; m <<= 1) Ss += __shfl_xor(Ss, m, 16);
            if (c == 0)
                part[(size_t)(i0 + r + 16 * a) * 16 + jt] = make_float2(M, Ss);
        }
    }
    gbar(bar, tgt += 256);

    // ---- consensus steps
    for (int step = 0; step < NSTEP; ++step) {
        const float* rs   = rs_all + (size_t)step * N_S * R;
        const float* Pcur = step ? P1 : P0;
        float* out0 = (step == 0) ? out : nullptr;

        // P3: rt[j,k] += sum_i softmax(Shat)[i,j]*rs[i,k] (64 i x 64 j / block)
        {
            LdsRt& L = lds.rtl;
            const int j0 = (bid & 15) * 64;
            const int i0 = (bid >> 4) * 64;
            if (t < 64) {
                const float2* pr = part + (size_t)(i0 + t) * 16;
                float M = -1e30f, S = 0.f;
                float2 ps[16];
#pragma unroll
                for (int q = 0; q < 16; ++q) { ps[q] = pr[q]; M = fmaxf(M, ps[q].x); }
#pragma unroll
                for (int q = 0; q < 16; ++q) S += ps[q].y * __expf(ps[q].x - M);
                L.mrow[t] = M;
                L.irow[t] = 1.f / S;
            }
            __syncthreads();
            const int k = t & 31, jg = t >> 5;
            float acc[8] = {};
            for (int ic = 0; ic < 64; ic += 16) {
                {
                    int row = t >> 4, q = t & 15;   // 16 rows x 16 float4
                    int lr = ic + row;
                    float4 v = ((const float4*)(Shat + (size_t)(i0 + lr) * 1024 + j0))[q];
                    float m = L.mrow[lr], inv = L.irow[lr];
                    v.x = __expf(v.x - m) * inv;
                    v.y = __expf(v.y - m) * inv;
                    v.z = __expf(v.z - m) * inv;
                    v.w = __expf(v.w - m) * inv;
                    *(float4*)&L.Sl[row][q * 4] = v;
                    if (out0)
                        ((float4*)(out0 + (size_t)(i0 + lr) * 1024 + j0))[q] = v;
                }
                if (t < 128) {
                    int row = t >> 3, q = t & 7;   // 16 rows x 8 float4
                    *(float4*)&L.Rl[row][q * 4] =
                        ((const float4*)(rs + (size_t)(i0 + ic + row) * 32))[q];
                }
                __syncthreads();
#pragma unroll
                for (int ii = 0; ii < 16; ++ii) {
                    float rv = L.Rl[ii][k];
#pragma unroll
                    for (int m = 0; m < 8; ++m)
                        acc[m] += L.Sl[ii][jg * 8 + m] * rv;
                }
                __syncthreads();
            }
#pragma unroll
            for (int m = 0; m < 8; ++m)
                atomicAdd(&rt[(size_t)(j0 + jg * 8 + m) * 32 + k], acc[m]);
        }
        gbar(bar, tgt += 256);

        // P4: t-graph scatter
        {
            const int gid = bid * 256 + t;
            for (int v = gid; v < E_EDG * 32; v += 65536) {
                int k = v & 31, e = v >> 5;
                int src = et[e], dst = et[E_EDG + e];
                atomicAdd(&aggt[(size_t)dst * 32 + k], rt[(size_t)src * 32 + k]);
            }
        }
        gbar(bar, tgt += 256);

        // P5: Q = relu((rt+aggt)@W3+b3) @ Wm1  (blocks 0..127, 8 rows each)
        if (bid < 128) {
            LdsPost& L = lds.post;
            for (int s = t; s < 1024; s += 256) { L.w3[s] = W3[s]; L.wm1[s] = Wm1[s]; }
            const int row8 = t >> 5, k = t & 31;
            const int r = bid * 8 + row8;
            L.ul[row8][k] = rt[(size_t)r * 32 + k] + aggt[(size_t)r * 32 + k];
            __syncthreads();
            float acc = b3[k];
#pragma unroll
            for (int m = 0; m < 32; ++m) acc += L.ul[row8][m] * L.w3[m * 32 + k];
            L.ol[row8][k] = fmaxf(acc, 0.f);
            __syncthreads();
            float acc2 = 0.f;
#pragma unroll
            for (int m = 0; m < 32; ++m) acc2 += L.ol[row8][m] * L.wm1[m * 32 + k];
            Q[(size_t)r * 32 + k] = acc2;
        }
        gbar(bar, tgt += 256);

        // P6: Shat += delta, emit new partials; zero rt+aggt for next step
        {
            LdsDelta& L = lds.del;
            if (t < 64)   // rt+aggt contiguous: 65536 floats = 16384 float4
                ((float4*)rt)[bid * 64 + t] = make_float4(0.f, 0.f, 0.f, 0.f);
            const int i0 = (bid >> 4) * 64, j0 = (bid & 15) * 64, jt = bid & 15;
            for (int s = t; s < 64 * 8; s += 256) {
                int row = s >> 3, q = s & 7;
                *(float4*)&L.Pl[row][q * 4] =
                    ((const float4*)(Pcur + (size_t)(i0 + row) * 32))[q];
                *(float4*)&L.Ql[row][q * 4] =
                    ((const float4*)(Q + (size_t)(j0 + row) * 32))[q];
            }
            __syncthreads();
            const int r = t >> 4, c = t & 15;
            const float bv = bm2[0];
            float acc[4][4] = {};
#pragma unroll
            for (int q = 0; q < 8; ++q) {
                float4 w = ((const float4*)Wm2)[q];
                float4 pa[4], qb[4];
#pragma unroll
                for (int a = 0; a < 4; ++a) pa[a] = *(const float4*)&L.Pl[r + 16 * a][q * 4];
#pragma unroll
                for (int b = 0; b < 4; ++b) qb[b] = *(const float4*)&L.Ql[c + 16 * b][q * 4];
#pragma unroll
                for (int a = 0; a < 4; ++a)
#pragma unroll
                    for (int b = 0; b < 4; ++b)
                        acc[a][b] += w.x * fmaxf(pa[a].x - qb[b].x, 0.f)
                                   + w.y * fmaxf(pa[a].y - qb[b].y, 0.f)
                                   + w.z * fmaxf(pa[a].z - qb[b].z, 0.f)
                                   + w.w * fmaxf(pa[a].w - qb[b].w, 0.f);
            }
#pragma unroll
            for (int a = 0; a < 4; ++a) {
                float v[4];
#pragma unroll
                for (int b = 0; b < 4; ++b) {
                    size_t idx = (size_t)(i0 + r + 16 * a) * 1024 + (j0 + c + 16 * b);
                    v[b] = Shat[idx] + acc[a][b] + bv;
                    Shat[idx] = v[b];
                }
                float M = fmaxf(fmaxf(v[0], v[1]), fmaxf(v[2], v[3]));
#pragma unroll
                for (int m = 1; m < 16; m <<= 1) M = fmaxf(M, __shfl_xor(M, m, 16));
                float Ss = 0.f;
#pragma unroll
                for (int b = 0; b < 4; ++b) Ss += __expf(v[b] - M);
#pragma unroll
                for (int m = 1; m < 16; m <<= 1) Ss += __shfl_xor(Ss, m, 16);
                if (c == 0)
                    part[(size_t)(i0 + r + 16 * a) * 16 + jt] = make_float2(M, Ss);
            }
        }
        gbar(bar, tgt += 256);
    }

    // ---- P7: final softmax S_L from partials (4 rows/block)
    {
        float* out2 = out + (1 << 20);
        for (int rl = 0; rl < 4; ++rl) {
            const int i = bid * 4 + rl;
            const float2* pr = part + (size_t)i * 16;
            float M = -1e30f, S = 0.f;
            float2 ps[16];
#pragma unroll
            for (int q = 0; q < 16; ++q) { ps[q] = pr[q]; M = fmaxf(M, ps[q].x); }
#pragma unroll
            for (int q = 0; q < 16; ++q) S += ps[q].y * __expf(ps[q].x - M);
            const float inv = 1.f / S;
            const float* row = Shat + (size_t)i * 1024;
            float* o = out2 + (size_t)i * 1024;
#pragma unroll
            for (int j = 0; j < 4; ++j)
                o[t + 256 * j] = __expf(row[t + 256 * j] - M) * inv;
        }
    }
}

// ---------------------------------------------------------------------------
extern "C" void kernel_launch(void* const* d_in, const int* in_sizes, int n_in,
                              void* d_out, int out_size, void* d_ws, size_t ws_size,
                              hipStream_t stream) {
    const float* inputs = (const float*)d_in[0];
    const int*   idx1   = (const int*)d_in[1];
    const int*   idx2   = (const int*)d_in[2];
    const int*   es     = (const int*)d_in[3];
    const int*   et     = (const int*)d_in[4];
    const float* W1     = (const float*)d_in[5];
    const float* W2     = (const float*)d_in[6];
    const float* W3     = (const float*)d_in[7];
    const float* b3     = (const float*)d_in[8];
    const float* Wm1    = (const float*)d_in[9];
    const float* bm1    = (const float*)d_in[10];
    const float* Wm2    = (const float*)d_in[11];
    const float* bm2    = (const float*)d_in[12];
    const float* rs_all = (const float*)d_in[13];
    float* out = (float*)d_out;
    float* ws  = (float*)d_ws;

    // workspace layout (floats)
    float*  Shat  = ws;                       // 1,048,576
    float*  Ys    = Shat + (1 << 20);         // 131,072
    float*  G     = Ys + 131072;              // 16,384
    float2* part  = (float2*)(G + 16384);     // 32,768 floats
    float*  rt    = G + 16384 + 32768;        // 32,768  ┐ contiguous zero range
    float*  aggt  = rt + 32768;               // 32,768  │ (rt..aggs1)
    float*  aggs0 = aggt + 32768;             // 32,768  │
    float*  aggs1 = aggs0 + 32768;            // 32,768  ┘
    float*  P0    = aggs1 + 32768;            // 32,768
    float*  P1    = P0 + 32768;               // 32,768
    float*  Q     = P1 + 32768;               // 32,768
    unsigned* bar = (unsigned*)(Q + 32768);   // barrier counter (zeroed below)

    (void)hipMemsetAsync(bar, 0, 128, stream);
    mega<<<256, 256, 0, stream>>>(inputs, idx1, idx2, es, et, W1, W2, W3, b3,
                                  Wm1, bm1, Wm2, bm2, rs_all, out,
                                  Shat, part, Ys, G, rt, aggt, aggs0, aggs1,
                                  P0, P1, Q, bar);
}

// Round 6
// 279.183 us; speedup vs baseline: 2.6430x; 1.1918x over previous
//
#include <hip/hip_runtime.h>
#include <math.h>

#define N_S   1024
#define N_T   1024
#define C_IN  128
#define E_EDG 16384
#define R     32
#define NSTEP 2

// ---- phase-aliased LDS ------------------------------------------------------
struct LdsPre  { float wa[512]; float wt[64][129]; float red[256]; };
struct LdsYs   { float x[4][128]; };
struct LdsPost { float w3[1024]; float wm1[1024]; float ul[8][33]; float ol[8][33]; };
struct LdsShat { float As[64][132]; float Bs[64][132]; };
struct LdsRt   { float Sl[16][68]; float Rl[16][36]; float mrow[64]; float irow[64]; };
struct LdsDelta{ float Pl[64][36]; float Ql[64][36]; };
union  LdsAll  { LdsPre pre; LdsYs ys; LdsPost post; LdsShat shat; LdsRt rtl; LdsDelta del; };

// ---------------------------------------------------------------------------
// Two-level epoch barrier. Arrival: 8 group counters (128B apart; 32 RMWs
// per line, parallel across groups) -> root counter (8 RMWs). Last arriver
// resets counters and RELEASE-stores the epoch broadcast word. All blocks
// poll ONLY the epoch word (written once per barrier; no line bouncing with
// arrivals). Layout (unsigned idx): grp g at g*32, root at 256, epoch at 288.
// Co-residency: 256 blocks, 4 waves, 66KB LDS -> all resident; no deadlock.
// ---------------------------------------------------------------------------
__device__ __forceinline__ void gbar(unsigned* bar, unsigned ep) {
    __syncthreads();
    if (threadIdx.x == 0) {
        unsigned* gc  = bar + ((blockIdx.x >> 5) << 5);
        unsigned* rc  = bar + 256;
        unsigned* epw = bar + 288;
        unsigned prev = __hip_atomic_fetch_add(gc, 1u, __ATOMIC_ACQ_REL,
                                               __HIP_MEMORY_SCOPE_AGENT);
        if (prev == 31) {                        // last of this 32-block group
            unsigned r = __hip_atomic_fetch_add(rc, 1u, __ATOMIC_ACQ_REL,
                                                __HIP_MEMORY_SCOPE_AGENT);
            if (r == 7) {                        // last overall
                for (int i = 0; i < 8; ++i)      // reset for next barrier
                    __hip_atomic_store(bar + (i << 5), 0u, __ATOMIC_RELAXED,
                                       __HIP_MEMORY_SCOPE_AGENT);
                __hip_atomic_store(rc, 0u, __ATOMIC_RELAXED,
                                   __HIP_MEMORY_SCOPE_AGENT);
                __hip_atomic_store(epw, ep, __ATOMIC_RELEASE,
                                   __HIP_MEMORY_SCOPE_AGENT);
            }
        }
        unsigned spin = 0;
        while (__hip_atomic_load(epw, __ATOMIC_RELAXED,
                                 __HIP_MEMORY_SCOPE_AGENT) < ep) {
            __builtin_amdgcn_s_sleep(16);
            if (++spin > (1u << 20)) break;      // fail loud, not hung
        }
        __builtin_amdgcn_fence(__ATOMIC_ACQUIRE, "agent");
    }
    __syncthreads();
}

// ---------------------------------------------------------------------------
// One persistent kernel: 256 blocks x 256 threads, phases split by gbar().
// Phase math identical to the R3/R5 versions that passed correctness.
// ---------------------------------------------------------------------------
__global__ __launch_bounds__(256, 1) void mega(
    const float* __restrict__ inputs, const int* __restrict__ idx1,
    const int* __restrict__ idx2, const int* __restrict__ es,
    const int* __restrict__ et, const float* __restrict__ W1,
    const float* __restrict__ W2, const float* __restrict__ W3,
    const float* __restrict__ b3, const float* __restrict__ Wm1,
    const float* __restrict__ bm1, const float* __restrict__ Wm2,
    const float* __restrict__ bm2, const float* __restrict__ rs_all,
    float* out,
    float* Shat, float2* part, float* Ys, float* G,
    float* rt, float* aggt, float* aggs0, float* aggs1,
    float* P0, float* P1, float* Q, unsigned* bar) {

    __shared__ LdsAll lds;
    const int bid = blockIdx.x;
    const int t   = threadIdx.x;
    unsigned ep = 0;

    // ---- P0: G = W1 W1^T + W2 W2^T (blocks 0..127); zero rt..aggs1 (128..255)
    if (bid >= 128) {
        ((float4*)rt)[(bid - 128) * 256 + t] = make_float4(0.f, 0.f, 0.f, 0.f);
    } else {
        LdsPre& L = lds.pre;
        const int a = bid;
        for (int s = t; s < 512; s += 256)
            L.wa[s] = (s < 256) ? W1[a * 256 + s] : W2[a * 256 + (s - 256)];
        __syncthreads();
        float acc = 0.f;
        const int b = t & 127, h = t >> 7;
        for (int ci = 0; ci < 8; ++ci) {
            const float* Wsrc = (ci < 4) ? W1 : W2;
            const int cbase = (ci & 3) * 64;
#pragma unroll
            for (int it = 0; it < 8; ++it) {
                int s = it * 256 + t;
                int br = s >> 4, q = s & 15;
                float4 v = *(const float4*)(Wsrc + (size_t)br * 256 + cbase + q * 4);
                L.wt[q * 4 + 0][br] = v.x; L.wt[q * 4 + 1][br] = v.y;
                L.wt[q * 4 + 2][br] = v.z; L.wt[q * 4 + 3][br] = v.w;
            }
            __syncthreads();
            const float* wac = L.wa + ci * 64 + h * 32;
#pragma unroll
            for (int cc = 0; cc < 32; ++cc)
                acc += wac[cc] * L.wt[h * 32 + cc][b];
            __syncthreads();
        }
        L.red[t] = acc;
        __syncthreads();
        if (t < 128) G[a * 128 + t] = L.red[t] + L.red[t + 128];
    }
    gbar(bar, ++ep);

    // ---- P1: Ys = X[idx1] @ G (4 rows/block)  +  s-graph scatter (both steps)
    {
        LdsYs& L = lds.ys;
        const int i0 = bid * 4;
        for (int s = t; s < 512; s += 256)
            L.x[s >> 7][s & 127] = inputs[(size_t)idx1[i0 + (s >> 7)] * 128 + (s & 127)];
        __syncthreads();
        const int lr = t >> 7, a = t & 127;
        for (int p = 0; p < 2; ++p) {
            const int row = p * 2 + lr;
            float acc = 0.f;
#pragma unroll 8
            for (int d = 0; d < 128; ++d) acc += L.x[row][d] * G[d * 128 + a];
            Ys[(size_t)(i0 + row) * 128 + a] = acc;
        }
    }
    {
        const int gid = bid * 256 + t;
        for (int v = gid; v < 2 * E_EDG * 32; v += 65536) {
            int k = v & 31, ei = v >> 5;
            int step = ei >> 14, e = ei & (E_EDG - 1);
            int src = es[e], dst = es[E_EDG + e];
            const float* rs = rs_all + (size_t)step * N_S * R;
            float* aggs = step ? aggs1 : aggs0;
            atomicAdd(&aggs[(size_t)dst * 32 + k], rs[(size_t)src * 32 + k]);
        }
    }
    gbar(bar, ++ep);

    // ---- P2: post_s (P0/P1 for both steps, 8 rows/block) then Shat tile
    {
        LdsPost& L = lds.post;
        for (int s = t; s < 1024; s += 256) { L.w3[s] = W3[s]; L.wm1[s] = Wm1[s]; }
        const int row8 = t >> 5, k = t & 31;
        const int grow = bid * 8 + row8;        // 0..2047
        const int step = grow >> 10, r = grow & 1023;
        const float* rs = rs_all + (size_t)step * N_S * R;
        const float* agg = step ? aggs1 : aggs0;
        float* P = step ? P1 : P0;
        L.ul[row8][k] = rs[(size_t)r * 32 + k] + agg[(size_t)r * 32 + k];
        __syncthreads();
        float acc = b3[k];
#pragma unroll
        for (int m = 0; m < 32; ++m) acc += L.ul[row8][m] * L.w3[m * 32 + k];
        L.ol[row8][k] = fmaxf(acc, 0.f);
        __syncthreads();
        float acc2 = bm1[k];
#pragma unroll
        for (int m = 0; m < 32; ++m) acc2 += L.ol[row8][m] * L.wm1[m * 32 + k];
        P[(size_t)r * 32 + k] = acc2;
        __syncthreads();                         // LDS reuse barrier
    }
    {
        LdsShat& L = lds.shat;
        const int i0 = (bid >> 4) * 64, j0 = (bid & 15) * 64, jt = bid & 15;
        for (int s = t; s < 64 * 32; s += 256) {
            int row = s >> 5, q = s & 31;
            *(float4*)&L.As[row][q * 4] =
                ((const float4*)(Ys + (size_t)(i0 + row) * 128))[q];
        }
        for (int s = t; s < 64 * 32; s += 256) {
            int row = s >> 5, q = s & 31;
            int src = idx2[j0 + row];
            *(float4*)&L.Bs[row][q * 4] =
                ((const float4*)(inputs + (size_t)src * 128))[q];
        }
        __syncthreads();
        const int r = t >> 4, c = t & 15;
        float acc[4][4] = {};
        for (int k = 0; k < 128; k += 4) {
            float4 ya[4], xb[4];
#pragma unroll
            for (int a = 0; a < 4; ++a) ya[a] = *(const float4*)&L.As[r + 16 * a][k];
#pragma unroll
            for (int b = 0; b < 4; ++b) xb[b] = *(const float4*)&L.Bs[c + 16 * b][k];
#pragma unroll
            for (int a = 0; a < 4; ++a)
#pragma unroll
                for (int b = 0; b < 4; ++b)
                    acc[a][b] += ya[a].x * xb[b].x + ya[a].y * xb[b].y +
                                 ya[a].z * xb[b].z + ya[a].w * xb[b].w;
        }
#pragma unroll
        for (int a = 0; a < 4; ++a) {
#pragma unroll
            for (int b = 0; b < 4; ++b)
                Shat[(size_t)(i0 + r + 16 * a) * 1024 + (j0 + c + 16 * b)] = acc[a][b];
            float M = fmaxf(fmaxf(acc[a][0], acc[a][1]), fmaxf(acc[a][2], acc[a][3]));
#pragma unroll
            for (int m = 1; m < 16; m <<= 1) M = fmaxf(M, __shfl_xor(M, m, 16));
            float Ss = 0.f;
#pragma unroll
            for (int b = 0; b < 4; ++b) Ss += __expf(acc[a][b] - M);
#pragma unroll
            for (int m = 1; m < 16; m <<= 1) Ss += __shfl_xor(Ss, m, 16);
            if (c == 0)
                part[(size_t)(i0 + r + 16 * a) * 16 + jt] = make_float2(M, Ss);
        }
    }
    gbar(bar, ++ep);

    // ---- consensus steps
    for (int step = 0; step < NSTEP; ++step) {
        const float* rs   = rs_all + (size_t)step * N_S * R;
        const float* Pcur = step ? P1 : P0;
        float* out0 = (step == 0) ? out : nullptr;

        // P3: rt[j,k] += sum_i softmax(Shat)[i,j]*rs[i,k] (64 i x 64 j / block)
        {
            LdsRt& L = lds.rtl;
            const int j0 = (bid & 15) * 64;
            const int i0 = (bid >> 4) * 64;
            if (t < 64) {
                const float2* pr = part + (size_t)(i0 + t) * 16;
                float M = -1e30f, S = 0.f;
                float2 ps[16];
#pragma unroll
                for (int q = 0; q < 16; ++q) { ps[q] = pr[q]; M = fmaxf(M, ps[q].x); }
#pragma unroll
                for (int q = 0; q < 16; ++q) S += ps[q].y * __expf(ps[q].x - M);
                L.mrow[t] = M;
                L.irow[t] = 1.f / S;
            }
            __syncthreads();
            const int k = t & 31, jg = t >> 5;
            float acc[8] = {};
            for (int ic = 0; ic < 64; ic += 16) {
                {
                    int row = t >> 4, q = t & 15;   // 16 rows x 16 float4
                    int lr = ic + row;
                    float4 v = ((const float4*)(Shat + (size_t)(i0 + lr) * 1024 + j0))[q];
                    float m = L.mrow[lr], inv = L.irow[lr];
                    v.x = __expf(v.x - m) * inv;
                    v.y = __expf(v.y - m) * inv;
                    v.z = __expf(v.z - m) * inv;
                    v.w = __expf(v.w - m) * inv;
                    *(float4*)&L.Sl[row][q * 4] = v;
                    if (out0)
                        ((float4*)(out0 + (size_t)(i0 + lr) * 1024 + j0))[q] = v;
                }
                if (t < 128) {
                    int row = t >> 3, q = t & 7;   // 16 rows x 8 float4
                    *(float4*)&L.Rl[row][q * 4] =
                        ((const float4*)(rs + (size_t)(i0 + ic + row) * 32))[q];
                }
                __syncthreads();
#pragma unroll
                for (int ii = 0; ii < 16; ++ii) {
                    float rv = L.Rl[ii][k];
#pragma unroll
                    for (int m = 0; m < 8; ++m)
                        acc[m] += L.Sl[ii][jg * 8 + m] * rv;
                }
                __syncthreads();
            }
#pragma unroll
            for (int m = 0; m < 8; ++m)
                atomicAdd(&rt[(size_t)(j0 + jg * 8 + m) * 32 + k], acc[m]);
        }
        gbar(bar, ++ep);

        // P4: t-graph scatter
        {
            const int gid = bid * 256 + t;
            for (int v = gid; v < E_EDG * 32; v += 65536) {
                int k = v & 31, e = v >> 5;
                int src = et[e], dst = et[E_EDG + e];
                atomicAdd(&aggt[(size_t)dst * 32 + k], rt[(size_t)src * 32 + k]);
            }
        }
        gbar(bar, ++ep);

        // P5: Q = relu((rt+aggt)@W3+b3) @ Wm1  (blocks 0..127, 8 rows each)
        if (bid < 128) {
            LdsPost& L = lds.post;
            for (int s = t; s < 1024; s += 256) { L.w3[s] = W3[s]; L.wm1[s] = Wm1[s]; }
            const int row8 = t >> 5, k = t & 31;
            const int r = bid * 8 + row8;
            L.ul[row8][k] = rt[(size_t)r * 32 + k] + aggt[(size_t)r * 32 + k];
            __syncthreads();
            float acc = b3[k];
#pragma unroll
            for (int m = 0; m < 32; ++m) acc += L.ul[row8][m] * L.w3[m * 32 + k];
            L.ol[row8][k] = fmaxf(acc, 0.f);
            __syncthreads();
            float acc2 = 0.f;
#pragma unroll
            for (int m = 0; m < 32; ++m) acc2 += L.ol[row8][m] * L.wm1[m * 32 + k];
            Q[(size_t)r * 32 + k] = acc2;
        }
        gbar(bar, ++ep);

        // P6: Shat += delta, emit new partials; zero rt+aggt for next step
        {
            LdsDelta& L = lds.del;
            if (t < 64)   // rt+aggt contiguous: 65536 floats = 16384 float4
                ((float4*)rt)[bid * 64 + t] = make_float4(0.f, 0.f, 0.f, 0.f);
            const int i0 = (bid >> 4) * 64, j0 = (bid & 15) * 64, jt = bid & 15;
            for (int s = t; s < 64 * 8; s += 256) {
                int row = s >> 3, q = s & 7;
                *(float4*)&L.Pl[row][q * 4] =
                    ((const float4*)(Pcur + (size_t)(i0 + row) * 32))[q];
                *(float4*)&L.Ql[row][q * 4] =
                    ((const float4*)(Q + (size_t)(j0 + row) * 32))[q];
            }
            __syncthreads();
            const int r = t >> 4, c = t & 15;
            const float bv = bm2[0];
            float acc[4][4] = {};
#pragma unroll
            for (int q = 0; q < 8; ++q) {
                float4 w = ((const float4*)Wm2)[q];
                float4 pa[4], qb[4];
#pragma unroll
                for (int a = 0; a < 4; ++a) pa[a] = *(const float4*)&L.Pl[r + 16 * a][q * 4];
#pragma unroll
                for (int b = 0; b < 4; ++b) qb[b] = *(const float4*)&L.Ql[c + 16 * b][q * 4];
#pragma unroll
                for (int a = 0; a < 4; ++a)
#pragma unroll
                    for (int b = 0; b < 4; ++b)
                        acc[a][b] += w.x * fmaxf(pa[a].x - qb[b].x, 0.f)
                                   + w.y * fmaxf(pa[a].y - qb[b].y, 0.f)
                                   + w.z * fmaxf(pa[a].z - qb[b].z, 0.f)
                                   + w.w * fmaxf(pa[a].w - qb[b].w, 0.f);
            }
#pragma unroll
            for (int a = 0; a < 4; ++a) {
                float v[4];
#pragma unroll
                for (int b = 0; b < 4; ++b) {
                    size_t idx = (size_t)(i0 + r + 16 * a) * 1024 + (j0 + c + 16 * b);
                    v[b] = Shat[idx] + acc[a][b] + bv;
                    Shat[idx] = v[b];
                }
                float M = fmaxf(fmaxf(v[0], v[1]), fmaxf(v[2], v[3]));
#pragma unroll
                for (int m = 1; m < 16; m <<= 1) M = fmaxf(M, __shfl_xor(M, m, 16));
                float Ss = 0.f;
#pragma unroll
                for (int b = 0; b < 4; ++b) Ss += __expf(v[b] - M);
#pragma unroll
                for (int m = 1; m < 16; m <<= 1) Ss += __shfl_xor(Ss, m, 16);
                if (c == 0)
                    part[(size_t)(i0 + r + 16 * a) * 16 + jt] = make_float2(M, Ss);
            }
        }
        gbar(bar, ++ep);
    }

    // ---- P7: final softmax S_L from partials (4 rows/block)
    {
        float* out2 = out + (1 << 20);
        for (int rl = 0; rl < 4; ++rl) {
            const int i = bid * 4 + rl;
            const float2* pr = part + (size_t)i * 16;
            float M = -1e30f, S = 0.f;
            float2 ps[16];
#pragma unroll
            for (int q = 0; q < 16; ++q) { ps[q] = pr[q]; M = fmaxf(M, ps[q].x); }
#pragma unroll
            for (int q = 0; q < 16; ++q) S += ps[q].y * __expf(ps[q].x - M);
            const float inv = 1.f / S;
            const float* row = Shat + (size_t)i * 1024;
            float* o = out2 + (size_t)i * 1024;
#pragma unroll
            for (int j = 0; j < 4; ++j)
                o[t + 256 * j] = __expf(row[t + 256 * j] - M) * inv;
        }
    }
}

// ---------------------------------------------------------------------------
extern "C" void kernel_launch(void* const* d_in, const int* in_sizes, int n_in,
                              void* d_out, int out_size, void* d_ws, size_t ws_size,
                              hipStream_t stream) {
    const float* inputs = (const float*)d_in[0];
    const int*   idx1   = (const int*)d_in[1];
    const int*   idx2   = (const int*)d_in[2];
    const int*   es     = (const int*)d_in[3];
    const int*   et     = (const int*)d_in[4];
    const float* W1     = (const float*)d_in[5];
    const float* W2     = (const float*)d_in[6];
    const float* W3     = (const float*)d_in[7];
    const float* b3     = (const float*)d_in[8];
    const float* Wm1    = (const float*)d_in[9];
    const float* bm1    = (const float*)d_in[10];
    const float* Wm2    = (const float*)d_in[11];
    const float* bm2    = (const float*)d_in[12];
    const float* rs_all = (const float*)d_in[13];
    float* out = (float*)d_out;
    float* ws  = (float*)d_ws;

    // workspace layout (floats)
    float*  Shat  = ws;                       // 1,048,576
    float*  Ys    = Shat + (1 << 20);         // 131,072
    float*  G     = Ys + 131072;              // 16,384
    float2* part  = (float2*)(G + 16384);     // 32,768 floats
    float*  rt    = G + 16384 + 32768;        // 32,768  ┐ contiguous zero range
    float*  aggt  = rt + 32768;               // 32,768  │ (rt..aggs1)
    float*  aggs0 = aggt + 32768;             // 32,768  │
    float*  aggs1 = aggs0 + 32768;            // 32,768  ┘
    float*  P0    = aggs1 + 32768;            // 32,768
    float*  P1    = P0 + 32768;               // 32,768
    float*  Q     = P1 + 32768;               // 32,768
    unsigned* bar = (unsigned*)(Q + 32768);   // 10x32 unsigned barrier state

    (void)hipMemsetAsync(bar, 0, 1280, stream);
    mega<<<256, 256, 0, stream>>>(inputs, idx1, idx2, es, et, W1, W2, W3, b3,
                                  Wm1, bm1, Wm2, bm2, rs_all, out,
                                  Shat, part, Ys, G, rt, aggt, aggs0, aggs1,
                                  P0, P1, Q, bar);
}